// Round 13
// baseline (800.398 us; speedup 1.0000x reference)
//
#include <hip/hip_runtime.h>
#include <hip/hip_bf16.h>
#include <stdint.h>

typedef __attribute__((ext_vector_type(8))) short short8;
typedef __attribute__((ext_vector_type(4))) float f32x4;
typedef __attribute__((ext_vector_type(4))) float float4v;
typedef __attribute__((ext_vector_type(4))) int int4v;

#define MDIM 8192
#define NDIM 11008
#define KDIM 4096
#define BKI  64                /* i8 K-tile */
#define NTI  (KDIM / BKI)      /* 64 K-tiles */
#define NBMI (MDIM / 128)      /* 64 */
#define NBNI (NDIM / 128)      /* 86 */
#define NC16 (NDIM / 16)       /* 688 fragment-column blocks */

// ws layout (bytes)
#define XQ_OFF  0ull
#define WQ_OFF  ((size_t)MDIM * KDIM)                 /* 33554432 */
#define SXT_OFF (WQ_OFF + (size_t)NDIM * KDIM)        /* + 45088768 */
#define SWT_OFF (SXT_OFF + 16ull * MDIM * 4)          /* + 524288 */
#define WS_NEED (SWT_OFF + 16ull * NDIM * 4)          /* ~79.9 MB */

static __device__ __forceinline__ unsigned short f2bf(float f) {
  union { float f; unsigned int u; } v;
  v.f = f;
  unsigned int r = v.u + 0x7FFFu + ((v.u >> 16) & 1u);
  return (unsigned short)(r >> 16);
}

#define GLDS16(g, l) __builtin_amdgcn_global_load_lds(                         \
    (const __attribute__((address_space(1))) void*)(g),                        \
    (__attribute__((address_space(3))) void*)(l), 16, 0, 0)

// ---------------- pass 1 (fused): x -> int8 groups  |  w -> fragment-linear i8
__global__ __launch_bounds__(256) void prep_all(
    const float* __restrict__ x, char* __restrict__ xq, float* __restrict__ sxT,
    const int* __restrict__ qw, const float* __restrict__ scale,
    char* __restrict__ wqf, float* __restrict__ swT) {
  const int t = threadIdx.x;
  if (blockIdx.x < MDIM) {
    const int row = blockIdx.x;
    const float* p = x + (size_t)row * KDIM + t * 16;
    float4v v[4];
#pragma unroll
    for (int c = 0; c < 4; ++c) v[c] = *(const float4v*)(p + c * 4);
    float amax = 0.f;
#pragma unroll
    for (int c = 0; c < 4; ++c)
#pragma unroll
      for (int e = 0; e < 4; ++e) amax = fmaxf(amax, fabsf(v[c][e]));
#pragma unroll
    for (int d = 1; d < 16; d <<= 1) amax = fmaxf(amax, __shfl_xor(amax, d));
    amax = fmaxf(amax, 1e-20f);
    if ((t & 15) == 0)
      sxT[(size_t)(t >> 4) * MDIM + row] = amax * (1.0f / 127.0f);
    const float inv = 127.0f / amax;
    int4v o;
#pragma unroll
    for (int c = 0; c < 4; ++c) {
      unsigned int r = 0;
#pragma unroll
      for (int e = 0; e < 4; ++e) {
        int q = __float2int_rn(v[c][e] * inv);
        r |= ((unsigned int)(q & 255)) << (8 * e);
      }
      o[c] = (int)r;
    }
    *(int4v*)(xq + (size_t)row * KDIM + t * 16) = o;
  } else {
    const int c16 = blockIdx.x - MDIM;       // 0..687
    const int lane = t & 63;
    const int l15 = lane & 15;
    const int lh  = (lane >> 4) & 3;
    const int col = c16 * 16 + l15;
    swT[(size_t)(t >> 4) * NDIM + c16 * 16 + (t & 15)] =
        1.0f / scale[(size_t)(c16 * 16 + (t & 15)) * 16 + (t >> 4)];
#pragma unroll
    for (int i = 0; i < 16; ++i) {
      const int kt = i * 4 + (t >> 6);       // 0..63, bijective over (i, t>>6)
      const int* src = qw + (size_t)col * KDIM + kt * 64 + lh * 16;
      int4v v[4];
#pragma unroll
      for (int c = 0; c < 4; ++c) v[c] = *(const int4v*)(src + c * 4);
      int4v o;
#pragma unroll
      for (int c = 0; c < 4; ++c) {
        unsigned int r = 0;
#pragma unroll
        for (int e = 0; e < 4; ++e) r |= ((unsigned int)(v[c][e] & 255)) << (8 * e);
        o[c] = (int)r;
      }
      *(int4v*)(wqf + ((size_t)c16 * NTI + kt) * 1024 + lane * 16) = o;
    }
  }
}

// ---------------- pass 2: 128x128 i8 GEMM, BARRIER-FREE wave-private pipeline
// 4 waves, wave tile 32x128. Each wave stages ONLY its own 32 A-rows into a
// private LDS region ([gran4][row16] layout -> contiguous 1KB ds_read, zero
// conflicts, r12-verified) and holds all 8 B col-fragments in registers
// (fragment-linear, distance-1 dbuf). NO s_barrier anywhere: waves free-run
// independent FIFO-counted pipelines. Steady: one vmcnt(12) per tile before
// the MFMA cluster (drains B(t) + A(t+1)); tail 12->12->8->0 exact.
__global__ __launch_bounds__(256, 2) void gemm_i8(
    const char* __restrict__ xq, const char* __restrict__ wqf,
    const float* __restrict__ sxT, const float* __restrict__ swT,
    const float* __restrict__ bias, float* __restrict__ out)
{
  __shared__ unsigned char lds[49152];
  unsigned char* ldsA = lds;              // [wave][4 bufs][2KB]: 32 rows x 64B
  float* sxl = (float*)(lds + 32768);     // [16][128] row scales
  float* swl = (float*)(lds + 40960);     // [16][128] col inv-scales

  const int t = threadIdx.x;
  const int lane = t & 63;
  const int w = t >> 6;        // wave 0..3 -> A rows w*32..w*32+31
  const int lh = lane >> 4;    // 0..3
  const int l15 = lane & 15;

  // XCD-bijective swizzle: 5504 = 8 * 688
  const int bid = blockIdx.x;
  const int swz = (bid & 7) * (NBMI * NBNI / 8) + (bid >> 3);
  const int bm = swz / NBNI;
  const int bn = swz % NBNI;

  // A staging: lane i fetches (row = i&15, gran = i>>4) of one 16-row strip
  const size_t srcOff = (size_t)l15 * KDIM + lh * 16;
  const char* aS = xq + ((size_t)(bm * 128 + w * 32)) * KDIM + srcOff;

  // B fragment-linear: wave reads ALL 8 col-fragments (dup across waves -> L1)
  const char* bqf = wqf + ((size_t)(bn * 8) * NTI) * 1024 + lane * 16;

  // bias: load early and pin (keep out of the counted vm queue)
  float bias_v[8];
#pragma unroll
  for (int n = 0; n < 8; ++n) {
    bias_v[n] = bias[bn * 128 + n * 16 + l15];
    asm volatile("" :: "v"(bias_v[n]));
  }

  // stage scale tables into LDS
  {
    const int tg = t >> 4;                 // 0..15
    const int tc = (t & 15) * 8;
    float4v a0 = *(const float4v*)(sxT + (size_t)tg * MDIM + bm * 128 + tc);
    float4v a1 = *(const float4v*)(sxT + (size_t)tg * MDIM + bm * 128 + tc + 4);
    float4v b0 = *(const float4v*)(swT + (size_t)tg * NDIM + bn * 128 + tc);
    float4v b1 = *(const float4v*)(swT + (size_t)tg * NDIM + bn * 128 + tc + 4);
    *(float4v*)(sxl + tg * 128 + tc)     = a0;
    *(float4v*)(sxl + tg * 128 + tc + 4) = a1;
    *(float4v*)(swl + tg * 128 + tc)     = b0;
    *(float4v*)(swl + tg * 128 + tc + 4) = b1;
  }
  __syncthreads();   // only barrier in the kernel: publish scale tables

  f32x4 accf[2][8];
  int4v acci[2][8];
#pragma unroll
  for (int m = 0; m < 2; ++m)
#pragma unroll
    for (int n = 0; n < 8; ++n) {
      accf[m][n] = (f32x4){0.f, 0.f, 0.f, 0.f};
      acci[m][n] = (int4v){0, 0, 0, 0};
    }

#define STAGE_A(buf, kt) {                                                     \
  GLDS16(aS + (kt) * BKI,             ldsA + w * 8192 + (buf) * 2048);         \
  GLDS16(aS + 16 * KDIM + (kt) * BKI, ldsA + w * 8192 + (buf) * 2048 + 1024); }

#define BLOAD(BARR, kt) {                                                      \
  _Pragma("unroll")                                                            \
  for (int n = 0; n < 8; ++n)                                                  \
    BARR[n] = *(const int4v*)(bqf + ((size_t)n * NTI + (kt)) * 1024); }

#define RD_A(buf, m) (*(const int4v*)(ldsA + w * 8192 + (buf) * 2048 +         \
                      (m) * 1024 + lh * 256 + l15 * 16))

#define VMW(N) asm volatile("s_waitcnt vmcnt(" N ")" ::: "memory");

// tile t (abuf = t&3): issue B(t+1)->BNXT then A(t+3); ds_read A(t);
// counted wait; 16 MFMA; optional fixup. NO barrier.
#define TILE(abuf, kt, BCUR, BNXT, DOLOADB, DOSTAGEA, WAITN, DOFIX) {          \
  if (DOLOADB) BLOAD(BNXT, (kt) + 1);                                          \
  __builtin_amdgcn_sched_barrier(0);                                           \
  if (DOSTAGEA) STAGE_A(((abuf) + 3) & 3, (kt) + 3);                           \
  __builtin_amdgcn_sched_barrier(0);                                           \
  int4v a[2];                                                                  \
  a[0] = RD_A(abuf, 0);                                                        \
  a[1] = RD_A(abuf, 1);                                                        \
  float4v sxv[2]; float swv[8];                                                \
  if (DOFIX) {                                                                 \
    const int g = (kt) >> 2;                                                   \
    _Pragma("unroll")                                                          \
    for (int m = 0; m < 2; ++m)                                                \
      sxv[m] = *(const float4v*)(sxl + g * 128 + w * 32 + m * 16 + lh * 4);    \
    _Pragma("unroll")                                                          \
    for (int n = 0; n < 8; ++n)                                                \
      swv[n] = swl[g * 128 + n * 16 + l15];                                    \
  }                                                                            \
  VMW(WAITN)                                                                   \
  __builtin_amdgcn_sched_barrier(0);                                           \
  __builtin_amdgcn_s_setprio(1);                                               \
  _Pragma("unroll")                                                            \
  for (int m = 0; m < 2; ++m)                                                  \
    _Pragma("unroll")                                                          \
    for (int n = 0; n < 8; ++n)                                                \
      acci[m][n] = __builtin_amdgcn_mfma_i32_16x16x64_i8(a[m], BCUR[n],        \
                                                         acci[m][n], 0, 0, 0); \
  __builtin_amdgcn_s_setprio(0);                                               \
  if (DOFIX) {                                                                 \
    _Pragma("unroll")                                                          \
    for (int m = 0; m < 2; ++m)                                                \
      _Pragma("unroll")                                                        \
      for (int n = 0; n < 8; ++n) {                                            \
        _Pragma("unroll")                                                      \
        for (int j = 0; j < 4; ++j)                                            \
          accf[m][n][j] += (float)acci[m][n][j] * (sxv[m][j] * swv[n]);        \
        acci[m][n] = (int4v){0, 0, 0, 0};                                      \
      }                                                                        \
  }                                                                            \
}

  int4v B0f[8], B1f[8];

  // prologue: [B0 x8, A0, A1, A2]; drain through A1 (leaves A2) -> vmcnt(2)
  BLOAD(B0f, 0);
  __builtin_amdgcn_sched_barrier(0);
  STAGE_A(0, 0);
  STAGE_A(1, 1);
  STAGE_A(2, 2);
  __builtin_amdgcn_sched_barrier(0);
  VMW("2")

  // steady: entering t: [A(t+1)2, B(t)8, A(t+2)2]; +10 issued; wait vmcnt(12)
  for (int kt = 0; kt < NTI - 4; kt += 4) {
    TILE(0, kt,     B0f, B1f, 1, 1, "12", 0)
    TILE(1, kt + 1, B1f, B0f, 1, 1, "12", 0)
    TILE(2, kt + 2, B0f, B1f, 1, 1, "12", 0)
    TILE(3, kt + 3, B1f, B0f, 1, 1, "12", 1)
  }
  // tail: t60 steady (stages A63); t61 B-only; t62 last B; t63 drain-all
  TILE(0, NTI - 4, B0f, B1f, 1, 1, "12", 0)
  TILE(1, NTI - 3, B1f, B0f, 1, 0, "12", 0)
  TILE(2, NTI - 2, B0f, B1f, 1, 0, "8",  0)
  TILE(3, NTI - 1, B1f, B0f, 0, 0, "0",  1)

  // epilogue: bias + fp32 store (C/D map: col=lane&15, row=(lane>>4)*4+j)
#pragma unroll
  for (int m = 0; m < 2; ++m) {
    const int row0 = bm * 128 + w * 32 + m * 16 + lh * 4;
#pragma unroll
    for (int n = 0; n < 8; ++n) {
      const int col = bn * 128 + n * 16 + l15;
      const float bv_ = bias_v[n];
#pragma unroll
      for (int j = 0; j < 4; ++j)
        out[(size_t)(row0 + j) * NDIM + col] = accf[m][n][j] + bv_;
    }
  }
#undef TILE
#undef VMW
#undef RD_A
#undef BLOAD
#undef STAGE_A
}

// ---------------- fallback: fused single-pass (round-1 kernel) ----------------
__global__ __launch_bounds__(256, 2) void clinear_fused(
    const float* __restrict__ x,
    const int* __restrict__ qw,
    const float* __restrict__ scale,
    const float* __restrict__ bias,
    float* __restrict__ out)
{
  __shared__ unsigned char ldsA[128 * 64 * 2];
  __shared__ unsigned char ldsB[128 * 64 * 2];

  const int t = threadIdx.x;
  const int lane = t & 63;
  const int wave = t >> 6;
  const int wr = wave >> 1;
  const int wc = wave & 1;

  const int NBN = NDIM / 128;
  const int bid = blockIdx.x;
  const int cpx = ((MDIM / 128) * NBN) >> 3;
  const int swz = (bid & 7) * cpx + (bid >> 3);
  const int bm = swz / NBN;
  const int bn = swz % NBN;

  const int srow = t >> 1;
  const int shalf = t & 1;
  const float* aptr = x  + (size_t)(bm * 128 + srow) * KDIM + shalf * 32;
  const int*   bptr = qw + (size_t)(bn * 128 + srow) * KDIM + shalf * 32;
  const float* sptr = scale + (size_t)(bn * 128 + srow) * (KDIM / 256);
  const int arx = srow & 7;

  f32x4 acc[4][4];
#pragma unroll
  for (int i = 0; i < 4; ++i)
#pragma unroll
    for (int j = 0; j < 4; ++j)
      acc[i][j] = (f32x4){0.f, 0.f, 0.f, 0.f};

  float bias_v[4];
#pragma unroll
  for (int n = 0; n < 4; ++n)
    bias_v[n] = bias[bn * 128 + wc * 64 + n * 16 + (lane & 15)];

  for (int kt = 0; kt < KDIM / 64; ++kt) {
    const int k0 = kt * 64;
    float4v av[8];
    int4v   bv[8];
#pragma unroll
    for (int j = 0; j < 8; ++j) av[j] = *(const float4v*)(aptr + k0 + 4 * j);
#pragma unroll
    for (int j = 0; j < 8; ++j) bv[j] = *(const int4v*)(bptr + k0 + 4 * j);
    const float inv = 1.0f / sptr[k0 >> 8];

    __syncthreads();
#pragma unroll
    for (int c = 0; c < 4; ++c) {
      short8 pa, pb;
#pragma unroll
      for (int e = 0; e < 8; ++e) {
        const int v = c * 8 + e;
        pa[e] = (short)f2bf(av[v >> 2][v & 3]);
        pb[e] = (short)f2bf((float)bv[v >> 2][v & 3] * inv);
      }
      const int cc = shalf * 4 + c;
      *(short8*)(ldsA + srow * 128 + ((cc ^ arx) << 4)) = pa;
      *(short8*)(ldsB + srow * 128 + ((cc ^ arx) << 4)) = pb;
    }
    __syncthreads();

    short8 af[4][2], bfr[4][2];
#pragma unroll
    for (int m = 0; m < 4; ++m) {
      const int r = wr * 64 + m * 16 + (lane & 15);
      const int rx = r & 7;
#pragma unroll
      for (int ks = 0; ks < 2; ++ks) {
        const int ch = ks * 4 + (lane >> 4);
        af[m][ks] = *(const short8*)(ldsA + r * 128 + ((ch ^ rx) << 4));
      }
    }
#pragma unroll
    for (int n = 0; n < 4; ++n) {
      const int r = wc * 64 + n * 16 + (lane & 15);
      const int rx = r & 7;
#pragma unroll
      for (int ks = 0; ks < 2; ++ks) {
        const int ch = ks * 4 + (lane >> 4);
        bfr[n][ks] = *(const short8*)(ldsB + r * 128 + ((ch ^ rx) << 4));
      }
    }
#pragma unroll
    for (int ks = 0; ks < 2; ++ks)
#pragma unroll
      for (int m = 0; m < 4; ++m)
#pragma unroll
        for (int n = 0; n < 4; ++n)
          acc[m][n] = __builtin_amdgcn_mfma_f32_16x16x32_bf16(
              af[m][ks], bfr[n][ks], acc[m][n], 0, 0, 0);
  }

#pragma unroll
  for (int m = 0; m < 4; ++m) {
    const int row0 = bm * 128 + wr * 64 + m * 16 + (lane >> 4) * 4;
#pragma unroll
    for (int n = 0; n < 4; ++n) {
      const int col = bn * 128 + wc * 64 + n * 16 + (lane & 15);
      const float bv_ = bias_v[n];
#pragma unroll
      for (int j = 0; j < 4; ++j)
        out[(size_t)(row0 + j) * NDIM + col] = acc[m][n][j] + bv_;
    }
  }
}

extern "C" void kernel_launch(void* const* d_in, const int* in_sizes, int n_in,
                              void* d_out, int out_size, void* d_ws, size_t ws_size,
                              hipStream_t stream) {
  const float* x     = (const float*)d_in[0];
  const int*   qw    = (const int*)d_in[1];
  const float* scale = (const float*)d_in[2];
  const float* bias  = (const float*)d_in[3];
  float* out = (float*)d_out;

  if (ws_size >= WS_NEED) {
    char*  xqb = (char*)d_ws + XQ_OFF;
    char*  wqf = (char*)d_ws + WQ_OFF;
    float* sxT = (float*)((char*)d_ws + SXT_OFF);
    float* swT = (float*)((char*)d_ws + SWT_OFF);
    hipLaunchKernelGGL(prep_all, dim3(MDIM + NC16), dim3(256), 0, stream,
                       x, xqb, sxT, qw, scale, wqf, swT);
    hipLaunchKernelGGL(gemm_i8, dim3(NBMI * NBNI), dim3(256), 0, stream,
                       xqb, wqf, sxT, swT, bias, out);
  } else {
    hipLaunchKernelGGL(clinear_fused, dim3((MDIM / 128) * (NDIM / 128)), dim3(256),
                       0, stream, x, qw, scale, bias, out);
  }
}

// Round 14
// 748.463 us; speedup vs baseline: 1.0694x; 1.0694x over previous
//
#include <hip/hip_runtime.h>
#include <hip/hip_bf16.h>
#include <stdint.h>

typedef __attribute__((ext_vector_type(8))) short short8;
typedef __attribute__((ext_vector_type(4))) float f32x4;
typedef __attribute__((ext_vector_type(4))) float float4v;
typedef __attribute__((ext_vector_type(4))) int int4v;

#define MDIM 8192
#define NDIM 11008
#define KDIM 4096
#define BKI  64                /* i8 K-tile */
#define NTI  (KDIM / BKI)      /* 64 K-tiles */
#define NBMI (MDIM / 128)      /* 64 */
#define NBNI (NDIM / 128)      /* 86 */

// ws layout (bytes)
#define XQ_OFF  0ull
#define WQ_OFF  ((size_t)MDIM * KDIM)                 /* 33554432 */
#define SXT_OFF (WQ_OFF + (size_t)NDIM * KDIM)        /* + 45088768 */
#define SWT_OFF (SXT_OFF + 16ull * MDIM * 4)          /* + 524288 */
#define WS_NEED (SWT_OFF + 16ull * NDIM * 4)          /* ~79.9 MB */

static __device__ __forceinline__ unsigned short f2bf(float f) {
  union { float f; unsigned int u; } v;
  v.f = f;
  unsigned int r = v.u + 0x7FFFu + ((v.u >> 16) & 1u);
  return (unsigned short)(r >> 16);
}

#define GLDS16(g, l) __builtin_amdgcn_global_load_lds(                         \
    (const __attribute__((address_space(1))) void*)(g),                        \
    (__attribute__((address_space(3))) void*)(l), 16, 0, 0)

// ---------------- pass 1 (fused): x -> int8 groups  |  qweight -> int8 pack --
// (r9-verified) sxT layout [g][MDIM]; swT layout [g][NDIM].
__global__ __launch_bounds__(256) void prep_all(
    const float* __restrict__ x, char* __restrict__ xq, float* __restrict__ sxT,
    const int* __restrict__ qw, const float* __restrict__ scale,
    char* __restrict__ wq, float* __restrict__ swT) {
  const int t = threadIdx.x;
  if (blockIdx.x < MDIM) {
    const int row = blockIdx.x;
    const float* p = x + (size_t)row * KDIM + t * 16;
    float4v v[4];
#pragma unroll
    for (int c = 0; c < 4; ++c) v[c] = *(const float4v*)(p + c * 4);
    float amax = 0.f;
#pragma unroll
    for (int c = 0; c < 4; ++c)
#pragma unroll
      for (int e = 0; e < 4; ++e) amax = fmaxf(amax, fabsf(v[c][e]));
#pragma unroll
    for (int d = 1; d < 16; d <<= 1) amax = fmaxf(amax, __shfl_xor(amax, d));
    amax = fmaxf(amax, 1e-20f);
    if ((t & 15) == 0)
      sxT[(size_t)(t >> 4) * MDIM + row] = amax * (1.0f / 127.0f);
    const float inv = 127.0f / amax;
    int4v o;
#pragma unroll
    for (int c = 0; c < 4; ++c) {
      unsigned int r = 0;
#pragma unroll
      for (int e = 0; e < 4; ++e) {
        int q = __float2int_rn(v[c][e] * inv);
        r |= ((unsigned int)(q & 255)) << (8 * e);
      }
      o[c] = (int)r;
    }
    *(int4v*)(xq + (size_t)row * KDIM + t * 16) = o;
  } else {
    const int row = blockIdx.x - MDIM;
    const int* p = qw + (size_t)row * KDIM + t * 16;
    int4v v[4];
#pragma unroll
    for (int c = 0; c < 4; ++c) v[c] = *(const int4v*)(p + c * 4);
    int4v o;
#pragma unroll
    for (int c = 0; c < 4; ++c) {
      unsigned int r = 0;
#pragma unroll
      for (int e = 0; e < 4; ++e) r |= ((unsigned int)(v[c][e] & 255)) << (8 * e);
      o[c] = (int)r;
    }
    *(int4v*)(wq + (size_t)row * KDIM + t * 16) = o;
    if ((t & 15) == 0)
      swT[(size_t)(t >> 4) * NDIM + row] = 1.0f / scale[(size_t)row * 16 + (t >> 4)];
  }
}

// ---------------- pass 2: 128x128 i8 GEMM = r9 schedule + zero-conflict LDS --
// 4 waves, wave tile 64x64, A+B shared via LDS (4-deep), per-tile barrier,
// counted vmcnt(8) steady / 8->4->0 tail, group-scale fixup from LDS.
// ONLY change vs r9: strip layout is [gran4][row16] (r12-verified) so every
// ds_read_b128 is one contiguous 1KB wave read -> ZERO bank conflicts.
__global__ __launch_bounds__(256, 2) void gemm_i8(
    const char* __restrict__ xq, const char* __restrict__ wq,
    const float* __restrict__ sxT, const float* __restrict__ swT,
    const float* __restrict__ bias, float* __restrict__ out)
{
  __shared__ unsigned char lds[81920];
  unsigned char* ldsA = lds;              // [4][8192]: 8 strips x [gran4][row16][16B]
  unsigned char* ldsB = lds + 32768;      // [4][8192]
  float* sxl = (float*)(lds + 65536);     // [16][128] row scales
  float* swl = (float*)(lds + 73728);     // [16][128] col inv-scales

  const int t = threadIdx.x;
  const int lane = t & 63;
  const int w = t >> 6;        // wave 0..3
  const int wr = w >> 1;       // 0..1  (A 64-row half)
  const int wc = w & 1;        // 0..1  (B 64-col half)
  const int lh = lane >> 4;    // 0..3
  const int l15 = lane & 15;

  // XCD-bijective swizzle: 5504 = 8 * 688
  const int bid = blockIdx.x;
  const int swz = (bid & 7) * (NBMI * NBNI / 8) + (bid >> 3);
  const int bm = swz / NBNI;
  const int bn = swz % NBNI;

  // staging: lane i fetches (row = i&15, gran = i>>4) of one 16-row strip;
  // LDS dest is linear lane*16 -> [gran][row] layout lands automatically.
  const size_t srcOff = (size_t)l15 * KDIM + lh * 16;
  const char* aS = xq + ((size_t)(bm * 128 + w * 32)) * KDIM + srcOff;
  const char* bS = wq + ((size_t)(bn * 128 + w * 32)) * KDIM + srcOff;

  // ---- prologue 1: stage scale tables into LDS ----
  {
    const int tg = t >> 4;                 // group 0..15
    const int tc = (t & 15) * 8;           // 8 floats each
    float4v a0 = *(const float4v*)(sxT + (size_t)tg * MDIM + bm * 128 + tc);
    float4v a1 = *(const float4v*)(sxT + (size_t)tg * MDIM + bm * 128 + tc + 4);
    float4v b0 = *(const float4v*)(swT + (size_t)tg * NDIM + bn * 128 + tc);
    float4v b1 = *(const float4v*)(swT + (size_t)tg * NDIM + bn * 128 + tc + 4);
    *(float4v*)(sxl + tg * 128 + tc)     = a0;
    *(float4v*)(sxl + tg * 128 + tc + 4) = a1;
    *(float4v*)(swl + tg * 128 + tc)     = b0;
    *(float4v*)(swl + tg * 128 + tc + 4) = b1;
  }
  __syncthreads();   // scale tables visible; vmcnt drained to 0

  float bias_v[4];
#pragma unroll
  for (int n = 0; n < 4; ++n) bias_v[n] = bias[bn * 128 + wc * 64 + n * 16 + l15];

  f32x4 accf[4][4];
  int4v acci[4][4];
#pragma unroll
  for (int m = 0; m < 4; ++m)
#pragma unroll
    for (int n = 0; n < 4; ++n) {
      accf[m][n] = (f32x4){0.f, 0.f, 0.f, 0.f};
      acci[m][n] = (int4v){0, 0, 0, 0};
    }

  // 4 loads/wave/tile: A strips (2w, 2w+1), B strips (2w, 2w+1)
#define STAGE(buf, kt) {                                                       \
  GLDS16(aS + (kt) * BKI,             ldsA + (buf) * 8192 + w * 2048);         \
  GLDS16(aS + 16 * KDIM + (kt) * BKI, ldsA + (buf) * 8192 + w * 2048 + 1024);  \
  GLDS16(bS + (kt) * BKI,             ldsB + (buf) * 8192 + w * 2048);         \
  GLDS16(bS + 16 * KDIM + (kt) * BKI, ldsB + (buf) * 8192 + w * 2048 + 1024); }

  // strip = half*4 + idx; contiguous per wave: gran lh, row l15 -> 0 conflicts
#define RD_A(buf, m) (*(const int4v*)(ldsA + (buf) * 8192 + wr * 4096 +        \
                      (m) * 1024 + lh * 256 + l15 * 16))
#define RD_B(buf, n) (*(const int4v*)(ldsB + (buf) * 8192 + wc * 4096 +        \
                      (n) * 1024 + lh * 256 + l15 * 16))

#define VMW(N) asm volatile("s_waitcnt vmcnt(" N ")" ::: "memory");

// tile t (buf = t&3): optionally stage tile t+3; read frags; 16 MFMA;
// fixup on t%4==3 (g = t>>2, scales from LDS); counted wait + barrier.
#define TILE(buf, kt, DOSTAGE, DOFIX, WAIT, DOBAR) {                           \
  if (DOSTAGE) STAGE(((buf) + 3) & 3, (kt) + 3);                               \
  int4v a[4], b[4];                                                            \
  _Pragma("unroll")                                                            \
  for (int i = 0; i < 4; ++i) a[i] = RD_A(buf, i);                             \
  _Pragma("unroll")                                                            \
  for (int n = 0; n < 4; ++n) b[n] = RD_B(buf, n);                             \
  float4v sxv[4]; float swv[4];                                                \
  if (DOFIX) {                                                                 \
    const int g = (kt) >> 2;                                                   \
    _Pragma("unroll")                                                          \
    for (int m = 0; m < 4; ++m)                                                \
      sxv[m] = *(const float4v*)(sxl + g * 128 + wr * 64 + m * 16 + lh * 4);   \
    _Pragma("unroll")                                                          \
    for (int n = 0; n < 4; ++n)                                                \
      swv[n] = swl[g * 128 + wc * 64 + n * 16 + l15];                          \
  }                                                                            \
  __builtin_amdgcn_s_setprio(1);                                               \
  _Pragma("unroll")                                                            \
  for (int m = 0; m < 4; ++m)                                                  \
    _Pragma("unroll")                                                          \
    for (int n = 0; n < 4; ++n)                                                \
      acci[m][n] = __builtin_amdgcn_mfma_i32_16x16x64_i8(a[m], b[n],           \
                                                         acci[m][n], 0, 0, 0); \
  __builtin_amdgcn_s_setprio(0);                                               \
  if (DOFIX) {                                                                 \
    _Pragma("unroll")                                                          \
    for (int m = 0; m < 4; ++m)                                                \
      _Pragma("unroll")                                                        \
      for (int n = 0; n < 4; ++n) {                                            \
        _Pragma("unroll")                                                      \
        for (int j = 0; j < 4; ++j)                                            \
          accf[m][n][j] += (float)acci[m][n][j] * (sxv[m][j] * swv[n]);        \
        acci[m][n] = (int4v){0, 0, 0, 0};                                      \
      }                                                                        \
  }                                                                            \
  WAIT                                                                         \
  if (DOBAR) __builtin_amdgcn_s_barrier(); }

  // ---- prologue 2: stage tiles 0,1,2 (12 loads); drain tile 0; publish ----
  STAGE(0, 0);
  STAGE(1, 1);
  STAGE(2, 2);
  VMW("8")
  __builtin_amdgcn_s_barrier();

  // steady state: wait vmcnt(8) each tile (2 tiles stay in flight)
  for (int kt = 0; kt < NTI - 4; kt += 4) {
    TILE(0, kt,     1, 0, VMW("8"), 1)
    TILE(1, kt + 1, 1, 0, VMW("8"), 1)
    TILE(2, kt + 2, 1, 0, VMW("8"), 1)
    TILE(3, kt + 3, 1, 1, VMW("8"), 1)
  }
  // tail: tile 60 stages 63; then exact drains 8 -> 4 -> 0
  TILE(0, NTI - 4, 1, 0, VMW("8"), 1)
  TILE(1, NTI - 3, 0, 0, VMW("4"), 1)
  TILE(2, NTI - 2, 0, 0, VMW("0"), 1)
  TILE(3, NTI - 1, 0, 1, , 0)

  // epilogue: bias + fp32 store (C/D map: col=lane&15, row=(lane>>4)*4+j)
#pragma unroll
  for (int m = 0; m < 4; ++m) {
    const int row0 = bm * 128 + wr * 64 + m * 16 + lh * 4;
#pragma unroll
    for (int n = 0; n < 4; ++n) {
      const int col = bn * 128 + wc * 64 + n * 16 + l15;
      const float bv_ = bias_v[n];
#pragma unroll
      for (int j = 0; j < 4; ++j)
        out[(size_t)(row0 + j) * NDIM + col] = accf[m][n][j] + bv_;
    }
  }
#undef TILE
#undef VMW
#undef RD_A
#undef RD_B
#undef STAGE
}

// ---------------- fallback: fused single-pass (round-1 kernel) ----------------
__global__ __launch_bounds__(256, 2) void clinear_fused(
    const float* __restrict__ x,
    const int* __restrict__ qw,
    const float* __restrict__ scale,
    const float* __restrict__ bias,
    float* __restrict__ out)
{
  __shared__ unsigned char ldsA[128 * 64 * 2];
  __shared__ unsigned char ldsB[128 * 64 * 2];

  const int t = threadIdx.x;
  const int lane = t & 63;
  const int wave = t >> 6;
  const int wr = wave >> 1;
  const int wc = wave & 1;

  const int NBN = NDIM / 128;
  const int bid = blockIdx.x;
  const int cpx = ((MDIM / 128) * NBN) >> 3;
  const int swz = (bid & 7) * cpx + (bid >> 3);
  const int bm = swz / NBN;
  const int bn = swz % NBN;

  const int srow = t >> 1;
  const int shalf = t & 1;
  const float* aptr = x  + (size_t)(bm * 128 + srow) * KDIM + shalf * 32;
  const int*   bptr = qw + (size_t)(bn * 128 + srow) * KDIM + shalf * 32;
  const float* sptr = scale + (size_t)(bn * 128 + srow) * (KDIM / 256);
  const int arx = srow & 7;

  f32x4 acc[4][4];
#pragma unroll
  for (int i = 0; i < 4; ++i)
#pragma unroll
    for (int j = 0; j < 4; ++j)
      acc[i][j] = (f32x4){0.f, 0.f, 0.f, 0.f};

  float bias_v[4];
#pragma unroll
  for (int n = 0; n < 4; ++n)
    bias_v[n] = bias[bn * 128 + wc * 64 + n * 16 + (lane & 15)];

  for (int kt = 0; kt < KDIM / 64; ++kt) {
    const int k0 = kt * 64;
    float4v av[8];
    int4v   bv[8];
#pragma unroll
    for (int j = 0; j < 8; ++j) av[j] = *(const float4v*)(aptr + k0 + 4 * j);
#pragma unroll
    for (int j = 0; j < 8; ++j) bv[j] = *(const int4v*)(bptr + k0 + 4 * j);
    const float inv = 1.0f / sptr[k0 >> 8];

    __syncthreads();
#pragma unroll
    for (int c = 0; c < 4; ++c) {
      short8 pa, pb;
#pragma unroll
      for (int e = 0; e < 8; ++e) {
        const int v = c * 8 + e;
        pa[e] = (short)f2bf(av[v >> 2][v & 3]);
        pb[e] = (short)f2bf((float)bv[v >> 2][v & 3] * inv);
      }
      const int cc = shalf * 4 + c;
      *(short8*)(ldsA + srow * 128 + ((cc ^ arx) << 4)) = pa;
      *(short8*)(ldsB + srow * 128 + ((cc ^ arx) << 4)) = pb;
    }
    __syncthreads();

    short8 af[4][2], bfr[4][2];
#pragma unroll
    for (int m = 0; m < 4; ++m) {
      const int r = wr * 64 + m * 16 + (lane & 15);
      const int rx = r & 7;
#pragma unroll
      for (int ks = 0; ks < 2; ++ks) {
        const int ch = ks * 4 + (lane >> 4);
        af[m][ks] = *(const short8*)(ldsA + r * 128 + ((ch ^ rx) << 4));
      }
    }
#pragma unroll
    for (int n = 0; n < 4; ++n) {
      const int r = wc * 64 + n * 16 + (lane & 15);
      const int rx = r & 7;
#pragma unroll
      for (int ks = 0; ks < 2; ++ks) {
        const int ch = ks * 4 + (lane >> 4);
        bfr[n][ks] = *(const short8*)(ldsB + r * 128 + ((ch ^ rx) << 4));
      }
    }
#pragma unroll
    for (int ks = 0; ks < 2; ++ks)
#pragma unroll
      for (int m = 0; m < 4; ++m)
#pragma unroll
        for (int n = 0; n < 4; ++n)
          acc[m][n] = __builtin_amdgcn_mfma_f32_16x16x32_bf16(
              af[m][ks], bfr[n][ks], acc[m][n], 0, 0, 0);
  }

#pragma unroll
  for (int m = 0; m < 4; ++m) {
    const int row0 = bm * 128 + wr * 64 + m * 16 + (lane >> 4) * 4;
#pragma unroll
    for (int n = 0; n < 4; ++n) {
      const int col = bn * 128 + wc * 64 + n * 16 + (lane & 15);
      const float bv_ = bias_v[n];
#pragma unroll
      for (int j = 0; j < 4; ++j)
        out[(size_t)(row0 + j) * NDIM + col] = acc[m][n][j] + bv_;
    }
  }
}

extern "C" void kernel_launch(void* const* d_in, const int* in_sizes, int n_in,
                              void* d_out, int out_size, void* d_ws, size_t ws_size,
                              hipStream_t stream) {
  const float* x     = (const float*)d_in[0];
  const int*   qw    = (const int*)d_in[1];
  const float* scale = (const float*)d_in[2];
  const float* bias  = (const float*)d_in[3];
  float* out = (float*)d_out;

  if (ws_size >= WS_NEED) {
    char*  xqb = (char*)d_ws + XQ_OFF;
    char*  wqb = (char*)d_ws + WQ_OFF;
    float* sxT = (float*)((char*)d_ws + SXT_OFF);
    float* swT = (float*)((char*)d_ws + SWT_OFF);
    hipLaunchKernelGGL(prep_all, dim3(MDIM + NDIM), dim3(256), 0, stream,
                       x, xqb, sxT, qw, scale, wqb, swT);
    hipLaunchKernelGGL(gemm_i8, dim3(NBMI * NBNI), dim3(256), 0, stream,
                       xqb, wqb, sxT, swT, bias, out);
  } else {
    hipLaunchKernelGGL(clinear_fused, dim3((MDIM / 128) * (NDIM / 128)), dim3(256),
                       0, stream, x, qw, scale, bias, out);
  }
}

// Round 15
// 606.784 us; speedup vs baseline: 1.3191x; 1.2335x over previous
//
#include <hip/hip_runtime.h>
#include <hip/hip_bf16.h>
#include <stdint.h>

typedef __attribute__((ext_vector_type(8))) short short8;
typedef __attribute__((ext_vector_type(4))) float f32x4;
typedef __attribute__((ext_vector_type(4))) float float4v;
typedef __attribute__((ext_vector_type(4))) int int4v;

#define MDIM 8192
#define NDIM 11008
#define KDIM 4096
#define BKI  64                /* i8 K-tile */
#define NTI  (KDIM / BKI)      /* 64 K-tiles */
#define NBMI (MDIM / 128)      /* 64 */
#define NBNI (NDIM / 128)      /* 86 */
#define NXB  (MDIM / 16)       /* 512 x row-blocks */

// ws layout (bytes)
#define AQ_OFF  0ull                                  /* A fragment-linear, 32 MB */
#define WQ_OFF  ((size_t)MDIM * KDIM)                 /* 33554432 */
#define SXT_OFF (WQ_OFF + (size_t)NDIM * KDIM)        /* + 45088768 */
#define SWT_OFF (SXT_OFF + 16ull * MDIM * 4)          /* + 524288 */
#define WS_NEED (SWT_OFF + 16ull * NDIM * 4)          /* ~79.9 MB */

static __device__ __forceinline__ unsigned short f2bf(float f) {
  union { float f; unsigned int u; } v;
  v.f = f;
  unsigned int r = v.u + 0x7FFFu + ((v.u >> 16) & 1u);
  return (unsigned short)(r >> 16);
}

#define GLDS16(g, l) __builtin_amdgcn_global_load_lds(                         \
    (const __attribute__((address_space(1))) void*)(g),                        \
    (__attribute__((address_space(3))) void*)(l), 16, 0, 0)

// ---------------- pass 1 (fused) ------------------------------------------
// blocks [0, NXB): 16 x-rows -> int8 quantized, FRAGMENT-LINEAR layout:
//   aqf[((r16*NTI + kt)<<10) + l*16] = x_q[r16*16 + (l&15)][kt*64+(l>>4)*16 ..]
// blocks [NXB, NXB+NDIM): w row -> row-major int8 pack + swT (r9-verified).
__global__ __launch_bounds__(256) void prep_all(
    const float* __restrict__ x, char* __restrict__ aqf, float* __restrict__ sxT,
    const int* __restrict__ qw, const float* __restrict__ scale,
    char* __restrict__ wq, float* __restrict__ swT) {
  const int t = threadIdx.x;
  if (blockIdx.x < NXB) {
    __shared__ char sq[16 * 272];        // 16 rows x 256B quantized (+16 pad)
    const int r16 = blockIdx.x;
    const int row = t >> 4;              // 0..15
    const int seg = t & 15;              // 16-float segment within group
    for (int j = 0; j < 16; ++j) {       // group j = cols [j*256, j*256+256)
      const float* p = x + ((size_t)(r16 * 16 + row)) * KDIM + j * 256 + seg * 16;
      float4v v[4];
#pragma unroll
      for (int c = 0; c < 4; ++c) v[c] = *(const float4v*)(p + c * 4);
      float amax = 0.f;
#pragma unroll
      for (int c = 0; c < 4; ++c)
#pragma unroll
        for (int e = 0; e < 4; ++e) amax = fmaxf(amax, fabsf(v[c][e]));
#pragma unroll
      for (int d = 1; d < 16; d <<= 1) amax = fmaxf(amax, __shfl_xor(amax, d));
      amax = fmaxf(amax, 1e-20f);
      if (seg == 0)
        sxT[(size_t)j * MDIM + r16 * 16 + row] = amax * (1.0f / 127.0f);
      const float inv = 127.0f / amax;
      int4v o;
#pragma unroll
      for (int c = 0; c < 4; ++c) {
        unsigned int r = 0;
#pragma unroll
        for (int e = 0; e < 4; ++e) {
          int q = __float2int_rn(v[c][e] * inv);
          r |= ((unsigned int)(q & 255)) << (8 * e);
        }
        o[c] = (int)r;
      }
      *(int4v*)(sq + row * 272 + seg * 16) = o;
      __syncthreads();
      // write fragment-linear: kt = j*4 + (t>>6), lane l = t&63
      {
        const int ktl = t >> 6;
        const int l = t & 63;
        int4v vv = *(const int4v*)(sq + (l & 15) * 272 + ktl * 64 + (l >> 4) * 16);
        *(int4v*)(aqf + (((size_t)r16 * NTI + j * 4 + ktl) << 10) + l * 16) = vv;
      }
      __syncthreads();
    }
  } else {
    const int row = blockIdx.x - NXB;
    const int* p = qw + (size_t)row * KDIM + t * 16;
    int4v v[4];
#pragma unroll
    for (int c = 0; c < 4; ++c) v[c] = *(const int4v*)(p + c * 4);
    int4v o;
#pragma unroll
    for (int c = 0; c < 4; ++c) {
      unsigned int r = 0;
#pragma unroll
      for (int e = 0; e < 4; ++e) r |= ((unsigned int)(v[c][e] & 255)) << (8 * e);
      o[c] = (int)r;
    }
    *(int4v*)(wq + (size_t)row * KDIM + t * 16) = o;
    if ((t & 15) == 0)
      swT[(size_t)(t >> 4) * NDIM + row] = 1.0f / scale[(size_t)row * 16 + (t >> 4)];
  }
}

// ---------------- pass 2: 128x128 i8 GEMM ----------------------------------
// A: fragment-linear direct-to-register (contiguous 1KB wave loads, no LDS).
// B: r9-verified LDS path (lane-adjacent GLDS source + XOR granule read).
// 4 waves, wave tile 64x64, per-tile barrier, FIFO-exact counted vmcnt:
// per tile issue [A(t+1) x4, B-stage(t+3) x2]; steady vmcnt(8) drains exactly
// {B(t+1) LDS publish, A(t) regs}; prologue vmcnt(8); tail 8->6->4->0.
__global__ __launch_bounds__(256, 2) void gemm_i8(
    const char* __restrict__ aqf, const char* __restrict__ wq,
    const float* __restrict__ sxT, const float* __restrict__ swT,
    const float* __restrict__ bias, float* __restrict__ out)
{
  __shared__ unsigned char lds[49152];
  unsigned char* ldsB = lds;              // [4][8192]: 8 strips x 16 rows x 64B
  float* sxl = (float*)(lds + 32768);     // [16][128] row scales
  float* swl = (float*)(lds + 40960);     // [16][128] col inv-scales

  const int t = threadIdx.x;
  const int lane = t & 63;
  const int w = t >> 6;        // wave 0..3
  const int wr = w >> 1;       // 0..1  (A 64-row half)
  const int wc = w & 1;        // 0..1  (B 64-col half)
  const int lh = lane >> 4;    // 0..3
  const int l15 = lane & 15;

  // XCD-bijective swizzle: 5504 = 8 * 688
  const int bid = blockIdx.x;
  const int swz = (bid & 7) * (NBMI * NBNI / 8) + (bid >> 3);
  const int bm = swz / NBNI;
  const int bn = swz % NBNI;

  // B staging (r9): lane-adjacent source, XOR granule
  const int srow16 = lane >> 2;
  const int q = (lane & 3) ^ (srow16 & 3) ^ ((srow16 >> 2) & 3);
  const size_t srcOff = (size_t)srow16 * KDIM + q * 16;
  const char* bS = wq + ((size_t)(bn * 128 + w * 32)) * KDIM + srcOff;
  const int f15 = (l15 & 3) ^ (l15 >> 2);

  // A fragment-linear base: wave's 4 row-blocks start at bm*8 + wr*4
  const char* aF = aqf + (((size_t)(bm * 8 + wr * 4) * NTI) << 10) + lane * 16;

  // bias: load early and pin (out of the counted vm queue; drained by syncthreads)
  float bias_v[4];
#pragma unroll
  for (int n = 0; n < 4; ++n) {
    bias_v[n] = bias[bn * 128 + wc * 64 + n * 16 + l15];
    asm volatile("" :: "v"(bias_v[n]));
  }

  // stage scale tables into LDS
  {
    const int tg = t >> 4;
    const int tc = (t & 15) * 8;
    float4v a0 = *(const float4v*)(sxT + (size_t)tg * MDIM + bm * 128 + tc);
    float4v a1 = *(const float4v*)(sxT + (size_t)tg * MDIM + bm * 128 + tc + 4);
    float4v b0 = *(const float4v*)(swT + (size_t)tg * NDIM + bn * 128 + tc);
    float4v b1 = *(const float4v*)(swT + (size_t)tg * NDIM + bn * 128 + tc + 4);
    *(float4v*)(sxl + tg * 128 + tc)     = a0;
    *(float4v*)(sxl + tg * 128 + tc + 4) = a1;
    *(float4v*)(swl + tg * 128 + tc)     = b0;
    *(float4v*)(swl + tg * 128 + tc + 4) = b1;
  }
  __syncthreads();   // publishes tables; drains vmcnt to 0

  f32x4 accf[4][4];
  int4v acci[4][4];
#pragma unroll
  for (int m = 0; m < 4; ++m)
#pragma unroll
    for (int n = 0; n < 4; ++n) {
      accf[m][n] = (f32x4){0.f, 0.f, 0.f, 0.f};
      acci[m][n] = (int4v){0, 0, 0, 0};
    }

#define ALOAD(ABUF, kt) {                                                      \
  _Pragma("unroll")                                                            \
  for (int m = 0; m < 4; ++m)                                                  \
    ABUF[m] = *(const int4v*)(aF + (((size_t)m * NTI + (kt)) << 10)); }

#define STAGE_B(buf, kt) {                                                     \
  GLDS16(bS + (kt) * BKI,             ldsB + (buf) * 8192 + w * 2048);         \
  GLDS16(bS + 16 * KDIM + (kt) * BKI, ldsB + (buf) * 8192 + w * 2048 + 1024); }

#define RD_B(buf, n) (*(const int4v*)(ldsB + (buf) * 8192 + wc * 4096 +        \
                      (n) * 1024 + l15 * 64 + ((lh ^ f15) << 4)))

#define VMW(N) asm volatile("s_waitcnt vmcnt(" N ")" ::: "memory");

// tile t (bbuf = t&3): issue A(t+1)->ANXT, B-stage(t+3); ds_read B(t);
// counted wait; 16 MFMA on ACUR; optional fixup; barrier.
#define TILE(bbuf, kt, ACUR, ANXT, DOLOADA, DOSTAGEB, WAITN, DOFIX, DOBAR) {   \
  if (DOLOADA) ALOAD(ANXT, (kt) + 1);                                          \
  __builtin_amdgcn_sched_barrier(0);                                           \
  if (DOSTAGEB) STAGE_B(((bbuf) + 3) & 3, (kt) + 3);                           \
  __builtin_amdgcn_sched_barrier(0);                                           \
  int4v b[4];                                                                  \
  _Pragma("unroll")                                                            \
  for (int n = 0; n < 4; ++n) b[n] = RD_B(bbuf, n);                            \
  float4v sxv[4]; float swv[4];                                                \
  if (DOFIX) {                                                                 \
    const int g = (kt) >> 2;                                                   \
    _Pragma("unroll")                                                          \
    for (int m = 0; m < 4; ++m)                                                \
      sxv[m] = *(const float4v*)(sxl + g * 128 + wr * 64 + m * 16 + lh * 4);   \
    _Pragma("unroll")                                                          \
    for (int n = 0; n < 4; ++n)                                                \
      swv[n] = swl[g * 128 + wc * 64 + n * 16 + l15];                          \
  }                                                                            \
  VMW(WAITN)                                                                   \
  __builtin_amdgcn_sched_barrier(0);                                           \
  __builtin_amdgcn_s_setprio(1);                                               \
  _Pragma("unroll")                                                            \
  for (int m = 0; m < 4; ++m)                                                  \
    _Pragma("unroll")                                                          \
    for (int n = 0; n < 4; ++n)                                                \
      acci[m][n] = __builtin_amdgcn_mfma_i32_16x16x64_i8(ACUR[m], b[n],        \
                                                         acci[m][n], 0, 0, 0); \
  __builtin_amdgcn_s_setprio(0);                                               \
  if (DOFIX) {                                                                 \
    _Pragma("unroll")                                                          \
    for (int m = 0; m < 4; ++m)                                                \
      _Pragma("unroll")                                                        \
      for (int n = 0; n < 4; ++n) {                                            \
        _Pragma("unroll")                                                      \
        for (int j = 0; j < 4; ++j)                                            \
          accf[m][n][j] += (float)acci[m][n][j] * (sxv[m][j] * swv[n]);        \
        acci[m][n] = (int4v){0, 0, 0, 0};                                      \
      }                                                                        \
  }                                                                            \
  if (DOBAR) __builtin_amdgcn_s_barrier(); }

  int4v A0f[4], A1f[4];

  // prologue (FIFO matches steady): B0, B1, A0, B2; drain B0 -> vmcnt(8)
  STAGE_B(0, 0);
  STAGE_B(1, 1);
  __builtin_amdgcn_sched_barrier(0);
  ALOAD(A0f, 0);
  __builtin_amdgcn_sched_barrier(0);
  STAGE_B(2, 2);
  __builtin_amdgcn_sched_barrier(0);
  VMW("8")
  __builtin_amdgcn_s_barrier();

  // steady: entering t: [B(t+1)2, A(t)4, B(t+2)2]=8; +6; vmcnt(8) drains
  // B(t+1)+A(t) exactly.
  for (int kt = 0; kt < NTI - 4; kt += 4) {
    TILE(0, kt,     A0f, A1f, 1, 1, "8", 0, 1)
    TILE(1, kt + 1, A1f, A0f, 1, 1, "8", 0, 1)
    TILE(2, kt + 2, A0f, A1f, 1, 1, "8", 0, 1)
    TILE(3, kt + 3, A1f, A0f, 1, 1, "8", 1, 1)
  }
  // tail: t60 steady (stages B63); t61/62 no B-stage; t63 nothing
  TILE(0, NTI - 4, A0f, A1f, 1, 1, "8", 0, 1)
  TILE(1, NTI - 3, A1f, A0f, 1, 0, "6", 0, 1)
  TILE(2, NTI - 2, A0f, A1f, 1, 0, "4", 0, 1)
  TILE(3, NTI - 1, A1f, A0f, 0, 0, "0", 1, 0)

  // epilogue: bias + fp32 store (C/D map: col=lane&15, row=(lane>>4)*4+j)
#pragma unroll
  for (int m = 0; m < 4; ++m) {
    const int row0 = bm * 128 + wr * 64 + m * 16 + lh * 4;
#pragma unroll
    for (int n = 0; n < 4; ++n) {
      const int col = bn * 128 + wc * 64 + n * 16 + l15;
      const float bv_ = bias_v[n];
#pragma unroll
      for (int j = 0; j < 4; ++j)
        out[(size_t)(row0 + j) * NDIM + col] = accf[m][n][j] + bv_;
    }
  }
#undef TILE
#undef VMW
#undef RD_B
#undef STAGE_B
#undef ALOAD
}

// ---------------- fallback: fused single-pass (round-1 kernel) ----------------
__global__ __launch_bounds__(256, 2) void clinear_fused(
    const float* __restrict__ x,
    const int* __restrict__ qw,
    const float* __restrict__ scale,
    const float* __restrict__ bias,
    float* __restrict__ out)
{
  __shared__ unsigned char ldsA[128 * 64 * 2];
  __shared__ unsigned char ldsB[128 * 64 * 2];

  const int t = threadIdx.x;
  const int lane = t & 63;
  const int wave = t >> 6;
  const int wr = wave >> 1;
  const int wc = wave & 1;

  const int NBN = NDIM / 128;
  const int bid = blockIdx.x;
  const int cpx = ((MDIM / 128) * NBN) >> 3;
  const int swz = (bid & 7) * cpx + (bid >> 3);
  const int bm = swz / NBN;
  const int bn = swz % NBN;

  const int srow = t >> 1;
  const int shalf = t & 1;
  const float* aptr = x  + (size_t)(bm * 128 + srow) * KDIM + shalf * 32;
  const int*   bptr = qw + (size_t)(bn * 128 + srow) * KDIM + shalf * 32;
  const float* sptr = scale + (size_t)(bn * 128 + srow) * (KDIM / 256);
  const int arx = srow & 7;

  f32x4 acc[4][4];
#pragma unroll
  for (int i = 0; i < 4; ++i)
#pragma unroll
    for (int j = 0; j < 4; ++j)
      acc[i][j] = (f32x4){0.f, 0.f, 0.f, 0.f};

  float bias_v[4];
#pragma unroll
  for (int n = 0; n < 4; ++n)
    bias_v[n] = bias[bn * 128 + wc * 64 + n * 16 + (lane & 15)];

  for (int kt = 0; kt < KDIM / 64; ++kt) {
    const int k0 = kt * 64;
    float4v av[8];
    int4v   bv[8];
#pragma unroll
    for (int j = 0; j < 8; ++j) av[j] = *(const float4v*)(aptr + k0 + 4 * j);
#pragma unroll
    for (int j = 0; j < 8; ++j) bv[j] = *(const int4v*)(bptr + k0 + 4 * j);
    const float inv = 1.0f / sptr[k0 >> 8];

    __syncthreads();
#pragma unroll
    for (int c = 0; c < 4; ++c) {
      short8 pa, pb;
#pragma unroll
      for (int e = 0; e < 8; ++e) {
        const int v = c * 8 + e;
        pa[e] = (short)f2bf(av[v >> 2][v & 3]);
        pb[e] = (short)f2bf((float)bv[v >> 2][v & 3] * inv);
      }
      const int cc = shalf * 4 + c;
      *(short8*)(ldsA + srow * 128 + ((cc ^ arx) << 4)) = pa;
      *(short8*)(ldsB + srow * 128 + ((cc ^ arx) << 4)) = pb;
    }
    __syncthreads();

    short8 af[4][2], bfr[4][2];
#pragma unroll
    for (int m = 0; m < 4; ++m) {
      const int r = wr * 64 + m * 16 + (lane & 15);
      const int rx = r & 7;
#pragma unroll
      for (int ks = 0; ks < 2; ++ks) {
        const int ch = ks * 4 + (lane >> 4);
        af[m][ks] = *(const short8*)(ldsA + r * 128 + ((ch ^ rx) << 4));
      }
    }
#pragma unroll
    for (int n = 0; n < 4; ++n) {
      const int r = wc * 64 + n * 16 + (lane & 15);
      const int rx = r & 7;
#pragma unroll
      for (int ks = 0; ks < 2; ++ks) {
        const int ch = ks * 4 + (lane >> 4);
        bfr[n][ks] = *(const short8*)(ldsB + r * 128 + ((ch ^ rx) << 4));
      }
    }
#pragma unroll
    for (int ks = 0; ks < 2; ++ks)
#pragma unroll
      for (int m = 0; m < 4; ++m)
#pragma unroll
        for (int n = 0; n < 4; ++n)
          acc[m][n] = __builtin_amdgcn_mfma_f32_16x16x32_bf16(
              af[m][ks], bfr[n][ks], acc[m][n], 0, 0, 0);
  }

#pragma unroll
  for (int m = 0; m < 4; ++m) {
    const int row0 = bm * 128 + wr * 64 + m * 16 + (lane >> 4) * 4;
#pragma unroll
    for (int n = 0; n < 4; ++n) {
      const int col = bn * 128 + wc * 64 + n * 16 + (lane & 15);
      const float bv_ = bias_v[n];
#pragma unroll
      for (int j = 0; j < 4; ++j)
        out[(size_t)(row0 + j) * NDIM + col] = acc[m][n][j] + bv_;
    }
  }
}

extern "C" void kernel_launch(void* const* d_in, const int* in_sizes, int n_in,
                              void* d_out, int out_size, void* d_ws, size_t ws_size,
                              hipStream_t stream) {
  const float* x     = (const float*)d_in[0];
  const int*   qw    = (const int*)d_in[1];
  const float* scale = (const float*)d_in[2];
  const float* bias  = (const float*)d_in[3];
  float* out = (float*)d_out;

  if (ws_size >= WS_NEED) {
    char*  aqf = (char*)d_ws + AQ_OFF;
    char*  wqb = (char*)d_ws + WQ_OFF;
    float* sxT = (float*)((char*)d_ws + SXT_OFF);
    float* swT = (float*)((char*)d_ws + SWT_OFF);
    hipLaunchKernelGGL(prep_all, dim3(NXB + NDIM), dim3(256), 0, stream,
                       x, aqf, sxT, qw, scale, wqb, swT);
    hipLaunchKernelGGL(gemm_i8, dim3(NBMI * NBNI), dim3(256), 0, stream,
                       aqf, wqb, sxT, swT, bias, out);
  } else {
    hipLaunchKernelGGL(clinear_fused, dim3((MDIM / 128) * (NDIM / 128)), dim3(256),
                       0, stream, x, qw, scale, bias, out);
  }
}